// Round 12
// baseline (173.519 us; speedup 1.0000x reference)
//
#include <hip/hip_runtime.h>
#include <hip/hip_bf16.h>
#include <hip/hip_fp16.h>
#include <cstdint>

#define DEVINL __device__ __forceinline__

typedef __attribute__((ext_vector_type(4))) float floatx4;
typedef __attribute__((ext_vector_type(8))) __bf16 bf16x8;
typedef __attribute__((ext_vector_type(4))) _Float16 half4;
typedef __attribute__((ext_vector_type(8))) _Float16 half8;
typedef __attribute__((ext_vector_type(4))) unsigned short u16x4;

DEVINL floatx4 mfma_16x16x32(bf16x8 a, bf16x8 b, floatx4 c) {
  return __builtin_amdgcn_mfma_f32_16x16x32_bf16(a, b, c, 0, 0, 0);
}
DEVINL floatx4 mfma_16x16x16_f16(half4 a, half4 b, floatx4 c) {
  return __builtin_amdgcn_mfma_f32_16x16x16f16(a, b, c, 0, 0, 0);
}

// async global->LDS, 16B per lane. LDS dest must be wave-uniform base + lane*16.
DEVINL void async_copy16(const void* g, void* l) {
  __builtin_amdgcn_global_load_lds(
      (__attribute__((address_space(1))) void*)(void*)g,
      (__attribute__((address_space(3))) void*)l, 16, 0, 0);
}

// Q scale: 1/sqrt(64) * log2(e), so softmax can use exp2 (bare v_exp_f32)
#define QSCALE 0.18033688011112042f

// XOR-swizzled fp16 64x64 scratch layout (row d, col s), 8 KB, conflict-light
#define VS(d, s) \
  ((d) * 128 + (((((s) >> 3)) ^ ((d) & 7)) << 4) + ((s) & 7) * 2)

// ---------------------------------------------------------------------------
// prep: one launch does x->bf16 cast (z==4) AND the four 1024x1024 weight
// transpose+casts (z=0..3). Grid (32,32,5), block (32,8).
// ---------------------------------------------------------------------------
__global__ void prep(const float* __restrict__ x, const float* __restrict__ Wq,
                     const float* __restrict__ Wk, const float* __restrict__ Wv,
                     const float* __restrict__ Wo,
                     __hip_bfloat16* __restrict__ xb,
                     __hip_bfloat16* __restrict__ Wt,
                     __hip_bfloat16* __restrict__ Wot) {
  const int z = blockIdx.z;
  const int tx = threadIdx.x, ty = threadIdx.y;  // (32,8)
  if (z == 4) {
    const int bi = blockIdx.y * 32 + blockIdx.x;   // [0,1024)
    const int tid = ty * 32 + tx;                  // [0,256)
    const int base = bi * 4096 + tid * 4;
#pragma unroll
    for (int j = 0; j < 4; ++j) {
      const int i = base + j * 1024;
      const float4 v = *(const float4*)&x[i];
      xb[i + 0] = __float2bfloat16(v.x);
      xb[i + 1] = __float2bfloat16(v.y);
      xb[i + 2] = __float2bfloat16(v.z);
      xb[i + 3] = __float2bfloat16(v.w);
    }
    return;
  }
  __shared__ float tile[32][33];
  const float* W = (z == 0) ? Wq : (z == 1) ? Wk : (z == 2) ? Wv : Wo;
  __hip_bfloat16* dst = (z < 3) ? (Wt + ((int64_t)z << 20)) : Wot;
  const int k0 = blockIdx.x * 32, n0 = blockIdx.y * 32;
#pragma unroll
  for (int i = 0; i < 32; i += 8)
    tile[ty + i][tx] = W[(int64_t)(k0 + ty + i) * 1024 + n0 + tx];
  __syncthreads();
#pragma unroll
  for (int i = 0; i < 32; i += 8)
    dst[(int64_t)(n0 + ty + i) * 1024 + k0 + tx] =
        __float2bfloat16(tile[tx][ty + i]);
}

// ---------------------------------------------------------------------------
// GEMM: C[M][N] = A[M][K] * Bt[N][K]^T  (bf16, MFMA 16x16x32), BK=64,
// XOR-swizzled LDS staging (chunk ^= row&7). TM x TN tile, 256 threads.
// MODE 0 (128x128): QKV epilogue (Q/K bf16 [B,H,S,64]; V fp16 transposed
//   through dead LDS -> Vt[B,H,64,S]).   MODE 1 (128x64): fp32 store.
// ---------------------------------------------------------------------------
template <int MODE, int TM, int TN>
__global__ __launch_bounds__(256, 2) void gemm_bt(
    const __hip_bfloat16* __restrict__ A, const __hip_bfloat16* __restrict__ Bt,
    int M, int N, int K, const float* __restrict__ bq,
    const float* __restrict__ bk, const float* __restrict__ bv,
    __hip_bfloat16* __restrict__ Qb, __hip_bfloat16* __restrict__ Kb,
    _Float16* __restrict__ Vt, float* __restrict__ outf) {
  constexpr int MI = TM / 32, NJ = TN / 32;  // acc tile dims per wave
  __shared__ __align__(16) char As[TM * 128];  // TM rows x 64 bf16
  __shared__ __align__(16) char Bs[TN * 128];
  const int tid = threadIdx.x;
  const int wave = tid >> 6, lane = tid & 63;
  const int quad = lane >> 4, l16 = lane & 15;
  const int bm = blockIdx.x * TM, bn = blockIdx.y * TN;
  const int wm = (wave >> 1) * (TM / 2), wn = (wave & 1) * (TN / 2);
  const int sw = l16 & 7;

  floatx4 acc[MI][NJ] = {};

  for (int k0 = 0; k0 < K; k0 += 64) {
#pragma unroll
    for (int i = 0; i < TM / 32; ++i) {
      const int p = tid + i * 256;
      const int r = p >> 3, cc = (p & 7) ^ (r & 7);
      async_copy16(A + (int64_t)(bm + r) * K + k0 + cc * 8, As + p * 16);
    }
#pragma unroll
    for (int i = 0; i < TN / 32; ++i) {
      const int p = tid + i * 256;
      const int r = p >> 3, cc = (p & 7) ^ (r & 7);
      async_copy16(Bt + (int64_t)(bn + r) * K + k0 + cc * 8, Bs + p * 16);
    }
    __syncthreads();
    bf16x8 af[MI][2], bfr[NJ][2];
#pragma unroll
    for (int i = 0; i < MI; ++i)
#pragma unroll
      for (int h = 0; h < 2; ++h)
        af[i][h] = *(const bf16x8*)(As + (wm + i * 16 + l16) * 128 +
                                    (((h * 4 + quad) ^ sw) << 4));
#pragma unroll
    for (int j = 0; j < NJ; ++j)
#pragma unroll
      for (int h = 0; h < 2; ++h)
        bfr[j][h] = *(const bf16x8*)(Bs + (wn + j * 16 + l16) * 128 +
                                     (((h * 4 + quad) ^ sw) << 4));
#pragma unroll
    for (int i = 0; i < MI; ++i)
#pragma unroll
      for (int j = 0; j < NJ; ++j)
#pragma unroll
        for (int h = 0; h < 2; ++h)
          acc[i][j] = mfma_16x16x32(af[i][h], bfr[j][h], acc[i][j]);
    __syncthreads();
  }

  if (MODE == 1) {
#pragma unroll
    for (int i = 0; i < MI; ++i)
#pragma unroll
      for (int j = 0; j < NJ; ++j) {
        const int n = bn + wn + j * 16 + l16;
#pragma unroll
        for (int r = 0; r < 4; ++r) {
          const int m = bm + wm + i * 16 + quad * 4 + r;
          outf[(int64_t)m * N + n] = acc[i][j][r];
        }
      }
  } else if (bn < 2048) {
    // ---- Q / K epilogue: bias (+QSCALE for Q), bf16 [B,H,S,64] ----
#pragma unroll
    for (int i = 0; i < MI; ++i)
#pragma unroll
      for (int j = 0; j < NJ; ++j) {
        const int n = bn + wn + j * 16 + l16;
        const int which = n >> 10, nn = n & 1023;
        const int h = nn >> 6, d = nn & 63;
        const float* bias = (which == 0) ? bq : bk;
#pragma unroll
        for (int r = 0; r < 4; ++r) {
          const int m = bm + wm + i * 16 + quad * 4 + r;
          const int b = m >> 11, s = m & 2047;
          float v = acc[i][j][r] + bias[nn];
          if (which == 0) v *= QSCALE;
          ((which == 0) ? Qb : Kb)[((int64_t)(b * 16 + h) * 2048 + s) * 64 + d] =
              __float2bfloat16(v);
        }
      }
  } else {
    // ---- V epilogue: LDS transpose -> Vt[B,H,64,S], coalesced rows ----
    char* scr = (wave & 1) ? Bs : As;  // >=8 KB per wave
    const int h = ((bn + wn) & 1023) >> 6;
    const int bb = (bm + wm) >> 11;
    const int sbase = (bm + wm) & 2047;
    _Float16* dstV = Vt + (int64_t)(bb * 16 + h) * 64 * 2048;
#pragma unroll
    for (int phase = 0; phase < 2; ++phase) {
      __syncthreads();
      if ((wave >> 1) == phase) {
#pragma unroll
        for (int i = 0; i < 4; ++i)
#pragma unroll
          for (int j = 0; j < 4; ++j) {
            const int d = j * 16 + l16;
#pragma unroll
            for (int r = 0; r < 4; ++r) {
              const int s = i * 16 + quad * 4 + r;
              *(_Float16*)(scr + VS(d, s)) =
                  (_Float16)(acc[i][j][r] + bv[((bn + wn) & 1023) + d]);
            }
          }
      }
      __syncthreads();
      if ((wave >> 1) == phase) {
#pragma unroll
        for (int it = 0; it < 8; ++it) {
          const int idx = lane + it * 64;  // [0,512)
          const int d = idx >> 3, sc = idx & 7;
          const half8 vv =
              *(const half8*)(scr + d * 128 + ((sc ^ (d & 7)) << 4));
          *(half8*)(dstV + (int64_t)d * 2048 + sbase + sc * 8) = vv;
        }
      }
    }
  }
}

// ---------------------------------------------------------------------------
// Flash attention v11, causal, SPLIT-K ACROSS BLOCKS (fixed-max softmax ->
// partial (o,l) over disjoint key ranges are exactly additive).
// Grid = 2048 blocks x 256 threads = (2 segs x 32 chunks, longest first) x 32
// (b*h). Chunk c covers tiles [0, c+1): seg0 = [0, ceil((c+1)/2)), seg1 =
// rest -> LONGEST SERIAL CHAIN 32 -> 16 tiles (v10's 45.5 us == the c=31
// chain; duration is chain-bound, not throughput-bound).
// 4 waves x 16-row strips (v9 shape: better tail-hiding than 2-wave v10).
// LDS-staged K/V DMA double buffer + transpose-free register P as before.
// seg0 writes fp16 un-normalized O at Ab's final addresses (dead xb region);
// seg1 to Of1 scratch; l's to the dead Wt region. attn_combine normalizes.
// ---------------------------------------------------------------------------
__global__ __launch_bounds__(256, 3) void attn_kernel(
    const __hip_bfloat16* __restrict__ Qb, const __hip_bfloat16* __restrict__ Kb,
    const _Float16* __restrict__ Vt, _Float16* __restrict__ Ap0,
    _Float16* __restrict__ Of1, float* __restrict__ L0,
    float* __restrict__ L1) {
  // [0,16K): K bufs (2 x 8 KB bf16 64x64)  [16K,32K): V bufs (2 x 8 KB fp16)
  __shared__ __align__(16) char smem[32768];
  const int tid = threadIdx.x;
  const int wave = tid >> 6, lane = tid & 63;
  const int quad = lane >> 4, l16 = lane & 15;
  const int idx = (int)(blockIdx.x >> 5);  // 0..63, long chunks first
  const int bh = blockIdx.x & 31;
  const int c = 31 - (idx >> 1);
  const int seg = idx & 1;
  const int nt = c + 1;
  const int n0 = (nt + 1) >> 1;            // seg0 tile count (>=1)
  const int ktmin = seg ? n0 : 0;
  const int ktend = seg ? nt : n0;         // exclusive; may equal ktmin (c=0 seg1)
  const int qbase = c * 64 + wave * 16;    // this wave's 16 Q rows

  const __hip_bfloat16* Qh = Qb + (int64_t)bh * 2048 * 64;
  const __hip_bfloat16* Kh = Kb + (int64_t)bh * 2048 * 64;
  const _Float16* Vh = Vt + (int64_t)bh * 64 * 2048;

  // Q B-fragments (16x16x32): Q[qrow=l16][d=h*32+quad*8+j]
  bf16x8 qf[2];
#pragma unroll
  for (int h = 0; h < 2; ++h)
    qf[h] = *(const bf16x8*)&Qh[(int64_t)(qbase + l16) * 64 + h * 32 + quad * 8];

  floatx4 o[4] = {};  // O^T[dt][C: row=d(quad*4+r), col=qrow(l16)]
  float lsum = 0.f;

  auto stage = [&](int buf, int k0s) {
#pragma unroll
    for (int i = 0; i < 2; ++i) {
      const int p = tid + i * 256;  // [0,512)
      const int r = p >> 3, cc = (p & 7) ^ (r & 7);
      async_copy16(Kh + (int64_t)(k0s + r) * 64 + cc * 8,
                   smem + buf * 8192 + p * 16);
      async_copy16(Vh + (int64_t)r * 2048 + k0s + cc * 8,
                   smem + 16384 + buf * 8192 + p * 16);
    }
  };

  if (ktend > ktmin) {
    stage(0, ktmin * 64);
    for (int kt = ktmin; kt < ktend; ++kt) {
      const int k0 = kt * 64;
      const int cur = (kt - ktmin) & 1;
      __syncthreads();  // buf[cur] DMA complete; prev tile's readers done
      if (kt + 1 < ktend) stage(cur ^ 1, k0 + 64);

      const char* kb = smem + cur * 8192;
      const char* vb = smem + 16384 + cur * 8192;
      const int sw = l16 & 7;

      bf16x8 kfr[4][2];
#pragma unroll
      for (int kk = 0; kk < 4; ++kk)
#pragma unroll
        for (int h = 0; h < 2; ++h)
          kfr[kk][h] = *(const bf16x8*)(kb + (kk * 16 + l16) * 128 +
                                        (((h * 4 + quad) ^ sw) << 4));

      // S^T = K Q^T : C holds S^T[key=quad*4+r][qrow=l16]
      floatx4 st[4];
#pragma unroll
      for (int kk = 0; kk < 4; ++kk) {
        floatx4 z = {};
        z = mfma_16x16x32(kfr[kk][0], qf[0], z);
        st[kk] = mfma_16x16x32(kfr[kk][1], qf[1], z);
      }

      half4 vfr[4][4];
#pragma unroll
      for (int dt = 0; dt < 4; ++dt)
#pragma unroll
        for (int kk = 0; kk < 4; ++kk)
          vfr[dt][kk] = *(const half4*)(vb + (dt * 16 + l16) * 128 +
                                        (((kk * 2 + (quad >> 1)) ^ sw) << 4) +
                                        (quad & 1) * 8);

      // P = exp2(S); causal mask only on the global diagonal tile (kt == c)
      const bool masked = (kt == c);
      half4 pf[4];
#pragma unroll
      for (int kk = 0; kk < 4; ++kk) {
#pragma unroll
        for (int r = 0; r < 4; ++r) {
          const int key = k0 + kk * 16 + quad * 4 + r;
          float p = __builtin_amdgcn_exp2f(st[kk][r]);
          if (masked && key > qbase + l16) p = 0.f;
          lsum += p;
          pf[kk][r] = (_Float16)p;
        }
      }

#pragma unroll
      for (int dt = 0; dt < 4; ++dt)
#pragma unroll
        for (int kk = 0; kk < 4; ++kk)
          o[dt] = mfma_16x16x16_f16(vfr[dt][kk], pf[kk], o[dt]);
    }
  }

  // ---- reduce l across the 4 quads per qrow; write partials ----
  lsum += __shfl_xor(lsum, 16, 64);
  lsum += __shfl_xor(lsum, 32, 64);
  const int chunk = bh * 32 + c;
  if (quad == 0)
    (seg ? L1 : L0)[chunk * 64 + wave * 16 + l16] = lsum;

  const int b = bh >> 4, h = bh & 15;
#pragma unroll
  for (int dt = 0; dt < 4; ++dt) {
    half4 pk;
#pragma unroll
    for (int r = 0; r < 4; ++r) pk[r] = (_Float16)o[dt][r];
    if (seg == 0)
      *(half4*)&Ap0[(int64_t)(b * 2048 + qbase + l16) * 1024 + h * 64 +
                    dt * 16 + quad * 4] = pk;
    else
      *(half4*)&Of1[((int64_t)chunk * 64 + wave * 16 + l16) * 64 + dt * 16 +
                    quad * 4] = pk;
  }
}

// ---------------------------------------------------------------------------
// Combine: Ab = bf16((o0 + o1) / (l0 + l1)), in place over the seg0 partial
// (Ap0 aliases Ab; each address owned by exactly one thread). 1024 blocks
// (one per chunk) x 256 threads, 16 elements each.
// ---------------------------------------------------------------------------
__global__ void attn_combine(const _Float16* __restrict__ Ap0,
                             const _Float16* __restrict__ Of1,
                             const float* __restrict__ L0,
                             const float* __restrict__ L1,
                             __hip_bfloat16* __restrict__ Ab) {
  const int chunk = blockIdx.x;  // bh*32 + c
  const int bh = chunk >> 5, c = chunk & 31;
  const int b = bh >> 4, h = bh & 15;
  const int qbase = c * 64;
  const int t = threadIdx.x;
  const int d = t & 63;
#pragma unroll
  for (int it = 0; it < 16; ++it) {
    const int row = it * 4 + (t >> 6);  // [0,64)
    const float l = L0[chunk * 64 + row] + L1[chunk * 64 + row];
    const int64_t a =
        (int64_t)(b * 2048 + qbase + row) * 1024 + h * 64 + d;
    const float o0 = (float)Ap0[a];
    const float o1 = (float)Of1[((int64_t)chunk * 64 + row) * 64 + d];
    Ab[a] = __float2bfloat16((o0 + o1) / l);
  }
}

// ---------------------------------------------------------------------------
// Workspace layout (bytes), 48 MB total (same max as prior rounds):
//   [0,  8M): xb (gemm0 input bf16) -> Ap0 (fp16 seg0 partial) -> Ab (bf16)
//   [8, 14M): Wt (dead after gemm0) -> L0 @8M, L1 @8M+256K
//   [14,16M): Wot (alive until gemm1)
//   [16,24M): Qb   [24,32M): Kb   [32,40M): Vt [B,H,64,S] fp16
//   [40,48M): Of1 (fp16 seg1 partial, chunk-major)
// ---------------------------------------------------------------------------
extern "C" void kernel_launch(void* const* d_in, const int* in_sizes, int n_in,
                              void* d_out, int out_size, void* d_ws,
                              size_t ws_size, hipStream_t stream) {
  const float* x = (const float*)d_in[0];
  const float* Wq = (const float*)d_in[1];
  const float* bq = (const float*)d_in[2];
  const float* Wk = (const float*)d_in[3];
  const float* bk = (const float*)d_in[4];
  const float* Wv = (const float*)d_in[5];
  const float* bv = (const float*)d_in[6];
  const float* Wo = (const float*)d_in[7];
  float* out = (float*)d_out;

  char* ws = (char*)d_ws;
  __hip_bfloat16* xb = (__hip_bfloat16*)(ws);
  __hip_bfloat16* Wt = (__hip_bfloat16*)(ws + (8ll << 20));
  __hip_bfloat16* Wot = (__hip_bfloat16*)(ws + (14ll << 20));
  __hip_bfloat16* Qb = (__hip_bfloat16*)(ws + (16ll << 20));
  __hip_bfloat16* Kb = (__hip_bfloat16*)(ws + (24ll << 20));
  _Float16* Vt = (_Float16*)(ws + (32ll << 20));
  _Float16* Of1 = (_Float16*)(ws + (40ll << 20));
  float* L0 = (float*)(ws + (8ll << 20));            // Wt dead after gemm0
  float* L1 = (float*)(ws + (8ll << 20) + (256 << 10));
  _Float16* Ap0 = (_Float16*)ws;                     // aliases xb/Ab
  __hip_bfloat16* Ab = xb;

  prep<<<dim3(32, 32, 5), dim3(32, 8), 0, stream>>>(x, Wq, Wk, Wv, Wo, xb, Wt,
                                                    Wot);
  gemm_bt<0, 128, 128><<<dim3(32, 24), 256, 0, stream>>>(
      xb, Wt, 4096, 3072, 1024, bq, bk, bv, Qb, Kb, Vt, nullptr);
  attn_kernel<<<dim3(2048), 256, 0, stream>>>(Qb, Kb, Vt, Ap0, Of1, L0, L1);
  attn_combine<<<dim3(1024), 256, 0, stream>>>(Ap0, Of1, L0, L1, Ab);
  gemm_bt<1, 128, 64><<<dim3(32, 16), 256, 0, stream>>>(
      Ab, Wot, 4096, 1024, 1024, nullptr, nullptr, nullptr, nullptr, nullptr,
      nullptr, out);
}

// Round 13
// 161.249 us; speedup vs baseline: 1.0761x; 1.0761x over previous
//
#include <hip/hip_runtime.h>
#include <hip/hip_bf16.h>
#include <hip/hip_fp16.h>
#include <cstdint>

#define DEVINL __device__ __forceinline__

typedef __attribute__((ext_vector_type(4))) float floatx4;
typedef __attribute__((ext_vector_type(8))) __bf16 bf16x8;
typedef __attribute__((ext_vector_type(4))) _Float16 half4;
typedef __attribute__((ext_vector_type(8))) _Float16 half8;
typedef __attribute__((ext_vector_type(4))) unsigned short u16x4;

DEVINL floatx4 mfma_16x16x32(bf16x8 a, bf16x8 b, floatx4 c) {
  return __builtin_amdgcn_mfma_f32_16x16x32_bf16(a, b, c, 0, 0, 0);
}
DEVINL floatx4 mfma_16x16x16_f16(half4 a, half4 b, floatx4 c) {
  return __builtin_amdgcn_mfma_f32_16x16x16f16(a, b, c, 0, 0, 0);
}

// async global->LDS, 16B per lane. LDS dest must be wave-uniform base + lane*16.
DEVINL void async_copy16(const void* g, void* l) {
  __builtin_amdgcn_global_load_lds(
      (__attribute__((address_space(1))) void*)(void*)g,
      (__attribute__((address_space(3))) void*)l, 16, 0, 0);
}

// Q scale: 1/sqrt(64) * log2(e), so softmax can use exp2 (bare v_exp_f32)
#define QSCALE 0.18033688011112042f

// XOR-swizzled fp16 64x64 scratch layout (row d, col s), 8 KB, conflict-light
#define VS(d, s) \
  ((d) * 128 + (((((s) >> 3)) ^ ((d) & 7)) << 4) + ((s) & 7) * 2)

// ---------------------------------------------------------------------------
// prep: one launch does x->bf16 cast (z==4) AND the four 1024x1024 weight
// transpose+casts (z=0..3). Grid (32,32,5), block (32,8).
// ---------------------------------------------------------------------------
__global__ void prep(const float* __restrict__ x, const float* __restrict__ Wq,
                     const float* __restrict__ Wk, const float* __restrict__ Wv,
                     const float* __restrict__ Wo,
                     __hip_bfloat16* __restrict__ xb,
                     __hip_bfloat16* __restrict__ Wt,
                     __hip_bfloat16* __restrict__ Wot) {
  const int z = blockIdx.z;
  const int tx = threadIdx.x, ty = threadIdx.y;  // (32,8)
  if (z == 4) {
    const int bi = blockIdx.y * 32 + blockIdx.x;   // [0,1024)
    const int tid = ty * 32 + tx;                  // [0,256)
    const int base = bi * 4096 + tid * 4;
#pragma unroll
    for (int j = 0; j < 4; ++j) {
      const int i = base + j * 1024;
      const float4 v = *(const float4*)&x[i];
      xb[i + 0] = __float2bfloat16(v.x);
      xb[i + 1] = __float2bfloat16(v.y);
      xb[i + 2] = __float2bfloat16(v.z);
      xb[i + 3] = __float2bfloat16(v.w);
    }
    return;
  }
  __shared__ float tile[32][33];
  const float* W = (z == 0) ? Wq : (z == 1) ? Wk : (z == 2) ? Wv : Wo;
  __hip_bfloat16* dst = (z < 3) ? (Wt + ((int64_t)z << 20)) : Wot;
  const int k0 = blockIdx.x * 32, n0 = blockIdx.y * 32;
#pragma unroll
  for (int i = 0; i < 32; i += 8)
    tile[ty + i][tx] = W[(int64_t)(k0 + ty + i) * 1024 + n0 + tx];
  __syncthreads();
#pragma unroll
  for (int i = 0; i < 32; i += 8)
    dst[(int64_t)(n0 + ty + i) * 1024 + k0 + tx] =
        __float2bfloat16(tile[tx][ty + i]);
}

// ---------------------------------------------------------------------------
// GEMM: C[M][N] = A[M][K] * Bt[N][K]^T  (bf16, MFMA 16x16x32), BK=64,
// XOR-swizzled LDS staging (chunk ^= row&7). TM x TN tile, 256 threads.
// MODE 0 (128x128, OCC=3): QKV epilogue. 768 blocks at 3 blocks/CU are all
//   co-resident in ONE dispatch round (at OCC=2 the grid ran as 512+256 with
//   half the CUs idle in round 2). VGPR cap 170 > ~130 live: no spill
//   expected -- canary is WRITE_SIZE (must stay ~24 MB).
// MODE 1 (128x64, OCC=2): plain fp32 store; 512 blocks = 1 round at 2/CU.
// ---------------------------------------------------------------------------
template <int MODE, int TM, int TN, int OCC>
__global__ __launch_bounds__(256, OCC) void gemm_bt(
    const __hip_bfloat16* __restrict__ A, const __hip_bfloat16* __restrict__ Bt,
    int M, int N, int K, const float* __restrict__ bq,
    const float* __restrict__ bk, const float* __restrict__ bv,
    __hip_bfloat16* __restrict__ Qb, __hip_bfloat16* __restrict__ Kb,
    _Float16* __restrict__ Vt, float* __restrict__ outf) {
  constexpr int MI = TM / 32, NJ = TN / 32;  // acc tile dims per wave
  __shared__ __align__(16) char As[TM * 128];  // TM rows x 64 bf16
  __shared__ __align__(16) char Bs[TN * 128];
  const int tid = threadIdx.x;
  const int wave = tid >> 6, lane = tid & 63;
  const int quad = lane >> 4, l16 = lane & 15;
  const int bm = blockIdx.x * TM, bn = blockIdx.y * TN;
  const int wm = (wave >> 1) * (TM / 2), wn = (wave & 1) * (TN / 2);
  const int sw = l16 & 7;

  floatx4 acc[MI][NJ] = {};

  for (int k0 = 0; k0 < K; k0 += 64) {
#pragma unroll
    for (int i = 0; i < TM / 32; ++i) {
      const int p = tid + i * 256;
      const int r = p >> 3, cc = (p & 7) ^ (r & 7);
      async_copy16(A + (int64_t)(bm + r) * K + k0 + cc * 8, As + p * 16);
    }
#pragma unroll
    for (int i = 0; i < TN / 32; ++i) {
      const int p = tid + i * 256;
      const int r = p >> 3, cc = (p & 7) ^ (r & 7);
      async_copy16(Bt + (int64_t)(bn + r) * K + k0 + cc * 8, Bs + p * 16);
    }
    __syncthreads();
    bf16x8 af[MI][2], bfr[NJ][2];
#pragma unroll
    for (int i = 0; i < MI; ++i)
#pragma unroll
      for (int h = 0; h < 2; ++h)
        af[i][h] = *(const bf16x8*)(As + (wm + i * 16 + l16) * 128 +
                                    (((h * 4 + quad) ^ sw) << 4));
#pragma unroll
    for (int j = 0; j < NJ; ++j)
#pragma unroll
      for (int h = 0; h < 2; ++h)
        bfr[j][h] = *(const bf16x8*)(Bs + (wn + j * 16 + l16) * 128 +
                                     (((h * 4 + quad) ^ sw) << 4));
#pragma unroll
    for (int i = 0; i < MI; ++i)
#pragma unroll
      for (int j = 0; j < NJ; ++j)
#pragma unroll
        for (int h = 0; h < 2; ++h)
          acc[i][j] = mfma_16x16x32(af[i][h], bfr[j][h], acc[i][j]);
    __syncthreads();
  }

  if (MODE == 1) {
#pragma unroll
    for (int i = 0; i < MI; ++i)
#pragma unroll
      for (int j = 0; j < NJ; ++j) {
        const int n = bn + wn + j * 16 + l16;
#pragma unroll
        for (int r = 0; r < 4; ++r) {
          const int m = bm + wm + i * 16 + quad * 4 + r;
          outf[(int64_t)m * N + n] = acc[i][j][r];
        }
      }
  } else if (bn < 2048) {
    // ---- Q / K epilogue: bias (+QSCALE for Q), bf16 [B,H,S,64] ----
#pragma unroll
    for (int i = 0; i < MI; ++i)
#pragma unroll
      for (int j = 0; j < NJ; ++j) {
        const int n = bn + wn + j * 16 + l16;
        const int which = n >> 10, nn = n & 1023;
        const int h = nn >> 6, d = nn & 63;
        const float* bias = (which == 0) ? bq : bk;
#pragma unroll
        for (int r = 0; r < 4; ++r) {
          const int m = bm + wm + i * 16 + quad * 4 + r;
          const int b = m >> 11, s = m & 2047;
          float v = acc[i][j][r] + bias[nn];
          if (which == 0) v *= QSCALE;
          ((which == 0) ? Qb : Kb)[((int64_t)(b * 16 + h) * 2048 + s) * 64 + d] =
              __float2bfloat16(v);
        }
      }
  } else {
    // ---- V epilogue: LDS transpose -> Vt[B,H,64,S], coalesced rows ----
    char* scr = (wave & 1) ? Bs : As;  // >=8 KB per wave
    const int h = ((bn + wn) & 1023) >> 6;
    const int bb = (bm + wm) >> 11;
    const int sbase = (bm + wm) & 2047;
    _Float16* dstV = Vt + (int64_t)(bb * 16 + h) * 64 * 2048;
#pragma unroll
    for (int phase = 0; phase < 2; ++phase) {
      __syncthreads();
      if ((wave >> 1) == phase) {
#pragma unroll
        for (int i = 0; i < 4; ++i)
#pragma unroll
          for (int j = 0; j < 4; ++j) {
            const int d = j * 16 + l16;
#pragma unroll
            for (int r = 0; r < 4; ++r) {
              const int s = i * 16 + quad * 4 + r;
              *(_Float16*)(scr + VS(d, s)) =
                  (_Float16)(acc[i][j][r] + bv[((bn + wn) & 1023) + d]);
            }
          }
      }
      __syncthreads();
      if ((wave >> 1) == phase) {
#pragma unroll
        for (int it = 0; it < 8; ++it) {
          const int idx = lane + it * 64;  // [0,512)
          const int d = idx >> 3, sc = idx & 7;
          const half8 vv =
              *(const half8*)(scr + d * 128 + ((sc ^ (d & 7)) << 4));
          *(half8*)(dstV + (int64_t)d * 2048 + sbase + sc * 8) = vv;
        }
      }
    }
  }
}

// ---------------------------------------------------------------------------
// Flash attention v13 == v9 (the best-measured shape), causal, single kernel.
// Round-12's split-K-across-blocks regressed: the combine kernel + extra
// launch + partial round-trip cost more than the chain shortening gained.
// Grid = 1024 blocks x 256 threads: 32 q-chunks of 64 rows (longest first)
// x 32 (b*h); 4 waves x 16-row strips (measured faster than 2-wave v10:
// ~38 vs 45.5 us). LDS-staged K/V DMA double buffer, one barrier per tile;
// transpose-free register P (S^T C-layout == PV B-operand layout).
// Softmax fixed-max m=0, exp2. XOR-swizzled staging.
// ---------------------------------------------------------------------------
__global__ __launch_bounds__(256, 3) void attn_kernel(
    const __hip_bfloat16* __restrict__ Qb, const __hip_bfloat16* __restrict__ Kb,
    const _Float16* __restrict__ Vt, __hip_bfloat16* __restrict__ Ab) {
  // [0,16K): K bufs (2 x 8 KB bf16 64x64)  [16K,32K): V bufs (2 x 8 KB fp16)
  __shared__ __align__(16) char smem[32768];
  const int tid = threadIdx.x;
  const int wave = tid >> 6, lane = tid & 63;
  const int quad = lane >> 4, l16 = lane & 15;
  const int c = 31 - (int)(blockIdx.x >> 5);  // long chunks dispatch first
  const int bh = blockIdx.x & 31;
  const int qbase = c * 64 + wave * 16;  // this wave's 16 Q rows
  const int ktmax = c;                   // uniform across waves

  const __hip_bfloat16* Qh = Qb + (int64_t)bh * 2048 * 64;
  const __hip_bfloat16* Kh = Kb + (int64_t)bh * 2048 * 64;
  const _Float16* Vh = Vt + (int64_t)bh * 64 * 2048;

  // Q B-fragments (16x16x32): Q[qrow=l16][d=h*32+quad*8+j]
  bf16x8 qf[2];
#pragma unroll
  for (int h = 0; h < 2; ++h)
    qf[h] = *(const bf16x8*)&Qh[(int64_t)(qbase + l16) * 64 + h * 32 + quad * 8];

  floatx4 o[4] = {};  // O^T[dt][C: row=d(quad*4+r), col=qrow(l16)]
  float lsum = 0.f;

  auto stage = [&](int buf, int k0s) {
#pragma unroll
    for (int i = 0; i < 2; ++i) {
      const int p = tid + i * 256;  // [0,512)
      const int r = p >> 3, cc = (p & 7) ^ (r & 7);
      async_copy16(Kh + (int64_t)(k0s + r) * 64 + cc * 8,
                   smem + buf * 8192 + p * 16);
      async_copy16(Vh + (int64_t)r * 2048 + k0s + cc * 8,
                   smem + 16384 + buf * 8192 + p * 16);
    }
  };

  stage(0, 0);
  for (int kt = 0; kt <= ktmax; ++kt) {
    const int k0 = kt * 64;
    const int cur = kt & 1;
    __syncthreads();  // buf[cur] DMA complete; prev tile's readers done
    if (kt < ktmax) stage(cur ^ 1, k0 + 64);

    const char* kb = smem + cur * 8192;
    const char* vb = smem + 16384 + cur * 8192;
    const int sw = l16 & 7;

    bf16x8 kfr[4][2];
#pragma unroll
    for (int kk = 0; kk < 4; ++kk)
#pragma unroll
      for (int h = 0; h < 2; ++h)
        kfr[kk][h] = *(const bf16x8*)(kb + (kk * 16 + l16) * 128 +
                                      (((h * 4 + quad) ^ sw) << 4));

    // S^T = K Q^T : C holds S^T[key=quad*4+r][qrow=l16]
    floatx4 st[4];
#pragma unroll
    for (int kk = 0; kk < 4; ++kk) {
      floatx4 z = {};
      z = mfma_16x16x32(kfr[kk][0], qf[0], z);
      st[kk] = mfma_16x16x32(kfr[kk][1], qf[1], z);
    }

    half4 vfr[4][4];
#pragma unroll
    for (int dt = 0; dt < 4; ++dt)
#pragma unroll
      for (int kk = 0; kk < 4; ++kk)
        vfr[dt][kk] = *(const half4*)(vb + (dt * 16 + l16) * 128 +
                                      (((kk * 2 + (quad >> 1)) ^ sw) << 4) +
                                      (quad & 1) * 8);

    // P = exp2(S), causal mask on diagonal tile; pack fp16 (B-operand layout)
    const bool masked = (kt == ktmax);
    half4 pf[4];
#pragma unroll
    for (int kk = 0; kk < 4; ++kk) {
#pragma unroll
      for (int r = 0; r < 4; ++r) {
        const int key = k0 + kk * 16 + quad * 4 + r;
        float p = __builtin_amdgcn_exp2f(st[kk][r]);
        if (masked && key > qbase + l16) p = 0.f;
        lsum += p;
        pf[kk][r] = (_Float16)p;
      }
    }

    // O^T += V^T P^T
#pragma unroll
    for (int dt = 0; dt < 4; ++dt)
#pragma unroll
      for (int kk = 0; kk < 4; ++kk)
        o[dt] = mfma_16x16x16_f16(vfr[dt][kk], pf[kk], o[dt]);
  }

  // ---- finalize: l is split across the 4 quads per qrow; reduce ----
  lsum += __shfl_xor(lsum, 16, 64);
  lsum += __shfl_xor(lsum, 32, 64);
  const float invl = 1.0f / lsum;

  // store bf16 [B,S,H*64]: row = qbase+l16, cols h*64 + dt*16 + quad*4 + r
  const int b = bh >> 4, h = bh & 15;
#pragma unroll
  for (int dt = 0; dt < 4; ++dt) {
    u16x4 pack;
#pragma unroll
    for (int r = 0; r < 4; ++r)
      pack[r] = __builtin_bit_cast(unsigned short,
                                   __float2bfloat16(o[dt][r] * invl));
    *(u16x4*)&Ab[(int64_t)(b * 2048 + qbase + l16) * 1024 + h * 64 + dt * 16 +
                 quad * 4] = pack;
  }
}

// ---------------------------------------------------------------------------
// Workspace layout (bytes), needs 40 MB:
//   [0,  8M): xb  (x as bf16, 4096x1024)  -- reused as Ab (attn out) later
//   [8, 14M): Wt  (Wq|Wk|Wv transposed bf16, 3072x1024)
//   [14,16M): Wot (Wo transposed bf16, 1024x1024)
//   [16,24M): Qb  [B,H,S,64] bf16 (pre-scaled by QSCALE)
//   [24,32M): Kb  [B,H,S,64] bf16
//   [32,40M): Vt  [B,H,64,S] fp16 (written directly by gemm_bt<0> epilogue)
// ---------------------------------------------------------------------------
extern "C" void kernel_launch(void* const* d_in, const int* in_sizes, int n_in,
                              void* d_out, int out_size, void* d_ws,
                              size_t ws_size, hipStream_t stream) {
  const float* x = (const float*)d_in[0];
  const float* Wq = (const float*)d_in[1];
  const float* bq = (const float*)d_in[2];
  const float* Wk = (const float*)d_in[3];
  const float* bk = (const float*)d_in[4];
  const float* Wv = (const float*)d_in[5];
  const float* bv = (const float*)d_in[6];
  const float* Wo = (const float*)d_in[7];
  float* out = (float*)d_out;

  char* ws = (char*)d_ws;
  __hip_bfloat16* xb = (__hip_bfloat16*)(ws);
  __hip_bfloat16* Wt = (__hip_bfloat16*)(ws + (8ll << 20));
  __hip_bfloat16* Wot = (__hip_bfloat16*)(ws + (14ll << 20));
  __hip_bfloat16* Qb = (__hip_bfloat16*)(ws + (16ll << 20));
  __hip_bfloat16* Kb = (__hip_bfloat16*)(ws + (24ll << 20));
  _Float16* Vt = (_Float16*)(ws + (32ll << 20));
  __hip_bfloat16* Ab = xb;  // x dead after QKV GEMM

  prep<<<dim3(32, 32, 5), dim3(32, 8), 0, stream>>>(x, Wq, Wk, Wv, Wo, xb, Wt,
                                                    Wot);
  gemm_bt<0, 128, 128, 3><<<dim3(32, 24), 256, 0, stream>>>(
      xb, Wt, 4096, 3072, 1024, bq, bk, bv, Qb, Kb, Vt, nullptr);
  attn_kernel<<<dim3(1024), 256, 0, stream>>>(Qb, Kb, Vt, Ab);
  gemm_bt<1, 128, 64, 2><<<dim3(32, 16), 256, 0, stream>>>(
      Ab, Wot, 4096, 1024, 1024, nullptr, nullptr, nullptr, nullptr, nullptr,
      nullptr, out);
}